// Round 8
// baseline (258.827 us; speedup 1.0000x reference)
//
#include <hip/hip_runtime.h>
#include <hip/hip_bf16.h>

// DynamicSlidingWindowAttention — flash attention, bf16 MFMA, gfx950.
// R19: 32 waves/CU via 8-wave blocks (2 q-halves x 4 KV-groups).
//  * R18 post-mortem: wave-private staging = 2x staging work + per-wave lgkm
//    serialization => regressed. R12's 2-wave-shared staging is right.
//  * R12-R18 constant: 16 waves/CU (LDS-bound), all pipes <30%, chain ~700cy
//    vs 2300cy/iter-slot => latency-bound, too few waves. This round doubles
//    waves/CU to 32 (8/SIMD max): block = 512 thr, 4 KV-groups; each group's
//    K+V tile SINGLE-buffered (9216 B) with 2 barriers/iter (stage->compute,
//    compute->next stage). Barrier density unchanged (1 per 64 keys); per-wave
//    chains halve (C/4); per-iteration wave body is verbatim R12.
//  * LDS: 4 x (2048K + 2560V shorts) = 36864 B; 4 blocks x 512 = 2048 thr/CU.
//  * Epilogue: 4-way partial merge via two 16.9 KB LDS areas (A=g1, B=g3;
//    g2 merges B into its regs, writes merged to A; g0 sums all, stores).
// R12 retained verbatim: preconv (K bf16 + V^T bf16), balanced static decode,
// Q frag load, S^T MFMA block, mask/exp, permlane32+16 P redistribution, PV
// reads, setprio.
// Layouts (m89/m91/m120-verified):
//   mfma_f32_16x16x32_bf16: A[m=lane&15][k=quad*8+j], B[k=quad*8+j][n=lane&15],
//   C/D: col=lane&15, row=quad*4+reg.

constexpr int Bc = 2, Hc = 16, Tc = 2048, Dc = 64;
constexpr int BQ = 64;            // q rows per block/item
constexpr int BK = 32;            // keys per kv tile
constexpr float QSCALE = 0.125f * 1.44269504088896340736f;  // 1/sqrt(d)*log2e
constexpr float CMAX = 16.0f;     // static softmax max (log2 domain)

// d_ws layout (bytes): [256,+8MiB) K bf16 | then V^T bf16
constexpr size_t KB_OFF = 256;
constexpr size_t VB_OFF = 256 + (size_t)Bc * Hc * Tc * Dc * 2;
constexpr int HEADE = Tc * Dc;

typedef __attribute__((ext_vector_type(8))) short short8;
typedef __attribute__((ext_vector_type(4))) float float4v;
typedef __attribute__((ext_vector_type(2))) unsigned int uint2v;

#if defined(__has_builtin)
#if __has_builtin(__builtin_amdgcn_exp2f)
#define EXP2 __builtin_amdgcn_exp2f
#endif
#endif
#ifndef EXP2
#define EXP2 exp2f
#endif

__device__ inline unsigned f2bf_u(float f) {
    union { float f; unsigned u; } v; v.f = f;
    return (v.u + 0x7fffu + ((v.u >> 16) & 1u)) >> 16;   // RNE
}

__device__ inline short8 pack8(const float* t) {
    short8 r;
#pragma unroll
    for (int j = 0; j < 8; j++) r[j] = (short)f2bf_u(t[j]);
    return r;
}

__device__ inline unsigned pk_bf16(float a, float b) {
    __hip_bfloat162 h = __float22bfloat162_rn(make_float2(a, b));
    union { __hip_bfloat162 h; unsigned u; } v; v.h = h;
    return v.u;
}

__device__ inline short8 mk8(unsigned a0, unsigned a1, unsigned a2, unsigned a3) {
    union { unsigned u[4]; short8 s; } v;
    v.u[0] = a0; v.u[1] = a1; v.u[2] = a2; v.u[3] = a3;
    return v.s;
}

// ---- pre-pass: K convert + V transpose-convert (R12 proven, verbatim) ----
__global__ __launch_bounds__(256)
void preconv_kernel(const float* __restrict__ K, const float* __restrict__ V,
                    unsigned short* __restrict__ Kb, unsigned short* __restrict__ Vtb) {
    const int blk = blockIdx.x;
    const int tid = threadIdx.x;
    if (blk < 2048) {
        const int base = blk * 2048 + tid * 8;
        float4v a = *(const float4v*)(K + base);
        float4v b = *(const float4v*)(K + base + 4);
        float t[8] = {a[0], a[1], a[2], a[3], b[0], b[1], b[2], b[3]};
        *(short8*)(Kb + base) = pack8(t);
    } else {
        __shared__ float tile[64][65];
        const int blk2 = blk - 2048;
        const int bh = blk2 >> 5;
        const int t0 = (blk2 & 31) * 64;
        const float* src = V + (size_t)bh * HEADE + (size_t)t0 * Dc;
#pragma unroll
        for (int i = 0; i < 4; i++) {
            const int r = (tid >> 4) + i * 16;
            const int d4 = (tid & 15) * 4;
            float4v v4 = *(const float4v*)(src + r * Dc + d4);
            tile[r][d4] = v4[0]; tile[r][d4 + 1] = v4[1];
            tile[r][d4 + 2] = v4[2]; tile[r][d4 + 3] = v4[3];
        }
        __syncthreads();
        unsigned short* dst = Vtb + (size_t)bh * HEADE + t0;
#pragma unroll
        for (int i = 0; i < 2; i++) {
            const int d = (tid >> 3) + 32 * i;
            const int c = tid & 7;
            float t[8];
#pragma unroll
            for (int j = 0; j < 8; j++) t[j] = tile[c * 8 + j][d];
            *(short8*)(dst + (size_t)d * Tc + c * 8) = pack8(t);
        }
    }
}

__global__ __launch_bounds__(512, 8)
void dswa_kernel(const float* __restrict__ Q,
                 const unsigned short* __restrict__ Kb,
                 const unsigned short* __restrict__ Vtb,
                 const int* __restrict__ wsz,
                 float* __restrict__ O) {
    __shared__ __align__(16) unsigned short LDS[18432];   // 36864 B

    const int tid  = threadIdx.x;
    const int wave = tid >> 6;          // 0..7
    const int g    = wave >> 1;         // kv-split group 0..3
    const int wq   = wave & 1;          // 32-row q half
    const int lane = tid & 63;
    const int quad = lane >> 4;
    const int l16  = lane & 15;

    unsigned short* Kg = &LDS[g * 2048];          // K [32][64] swizzled
    unsigned short* Vg = &LDS[8192 + g * 2560];   // V^T [64][40]

    // staging lane->chunk mapping (per group: waves {2g,2g+1} = 128 lanes
    // stage K 4 KB + V 4 KB) — tid>>7 == g, so tid&127 spans the group.
    const int l128 = tid & 127;
    const int krow = l128 >> 2;              // 0..31
    const int kcol = (l128 & 3) * 16;        // 16-element chunk base
    const int vrow = l128 >> 1;              // 0..63
    const int vcol = (l128 & 1) * 16;

    // ---- balanced static item decode (bijection on (b,h,qt), proven) ----
    const int blk  = blockIdx.x;
    const int ci   = blk & 255;
    const int slot = blk >> 8;               // 0=FULL,1=w1024,2=w512,3=w256
    const int b    = ci & 1;
    const int q5   = (ci >> 1) & 31;
    const int hh   = ci >> 6;
    const int h    = (3 - slot) * 4 + hh;
    const int qt   = (slot == 0) ? q5 : 31 - q5;
    const int q0   = qt * BQ;
    const int win  = wsz[h];

    const size_t headoff = (size_t)(b * Hc + h) * HEADE;
    const float* Qp = Q + headoff;
    const unsigned short* Kbh = Kb + headoff;
    const unsigned short* Vbh = Vtb + headoff;
    float* Op = O + headoff;

    // ---- Q fragments for both 16-row sets, pre-scaled (log2 domain) ----
    short8 qf[2][2];
#pragma unroll
    for (int s = 0; s < 2; s++) {
        const int qrow = q0 + wq * 32 + s * 16 + l16;
#pragma unroll
        for (int c = 0; c < 2; c++) {
            const float* src = Qp + (size_t)qrow * Dc + c * 32 + quad * 8;
            float4v a = *(const float4v*)src;
            float4v d4 = *(const float4v*)(src + 4);
            float t[8] = {a[0]*QSCALE, a[1]*QSCALE, a[2]*QSCALE, a[3]*QSCALE,
                          d4[0]*QSCALE, d4[1]*QSCALE, d4[2]*QSCALE, d4[3]*QSCALE};
            qf[s][c] = pack8(t);
        }
    }

    float4v acc[2][4];   // [set][nb] unnormalized O
#pragma unroll
    for (int s = 0; s < 2; s++)
#pragma unroll
        for (int nb = 0; nb < 4; nb++) acc[s][nb] = (float4v){0.f, 0.f, 0.f, 0.f};
    float lp0 = 0.0f, lp1 = 0.0f;

    const int kv_lo = (max(0, q0 - win)) & ~(BK - 1);
    const int C = (q0 + BQ - kv_lo) >> 5;    // 32-key tiles (>= 2)
    const int IT = (C + 3) >> 2;             // uniform loop bound (4 groups)

    // per-lane global source pointers (advance 4 tiles = 128 keys per iter)
    const int kv0g = kv_lo + g * BK;
    const unsigned short* kgp = Kbh + (size_t)(kv0g + krow) * Dc + kcol;
    const unsigned short* vgp = Vbh + (size_t)vrow * Tc + kv0g + vcol;

    // ---- prologue prefetch: tile g ----
    short8 kr0, kr1, vr0, vr1;
    if (g < C) {
        kr0 = *(const short8*)(kgp);
        kr1 = *(const short8*)(kgp + 8);
        vr0 = *(const short8*)(vgp);
        vr1 = *(const short8*)(vgp + 8);
    }
    kgp += 128 * Dc; vgp += 128;

    for (int t = 0; t < IT; ++t) {
        const int ti = g + 4 * t;
        const bool act = ti < C;
        const int kv0 = kv_lo + ti * BK;

        // ---- stage tile ti into group's single buffer (consumes prefetch) ----
        if (act) {
            const int ks = (krow & 7) << 3;
            *(short8*)&Kg[krow * 64 + (kcol ^ ks)] = kr0;
            *(short8*)&Kg[krow * 64 + ((kcol + 8) ^ ks)] = kr1;
            *(short8*)&Vg[vrow * 40 + vcol] = vr0;
            *(short8*)&Vg[vrow * 40 + vcol + 8] = vr1;
        }
        __syncthreads();   // A: staging visible before compute

        // ---- prefetch next visit (flies during this tile's compute) ----
        if (ti + 4 < C) {
            kr0 = *(const short8*)(kgp);
            kr1 = *(const short8*)(kgp + 8);
            vr0 = *(const short8*)(vgp);
            vr1 = *(const short8*)(vgp + 8);
        }
        kgp += 128 * Dc; vgp += 128;

        if (act) {
            // ---- S^T = K Q^T - CMAX, both sets share kf (2 mb x 2 ch) ----
            float4v sT0[2], sT1[2];
            __builtin_amdgcn_s_setprio(1);
#pragma unroll
            for (int mb = 0; mb < 2; mb++) {
                float4v c0 = {-CMAX, -CMAX, -CMAX, -CMAX};
                float4v c1 = {-CMAX, -CMAX, -CMAX, -CMAX};
#pragma unroll
                for (int ch = 0; ch < 2; ch++) {
                    const int row = mb * 16 + l16;
                    short8 kf = *(short8*)&Kg[row * 64 +
                                              ((ch * 32 + quad * 8) ^ ((row & 7) << 3))];
                    c0 = __builtin_amdgcn_mfma_f32_16x16x32_bf16(kf, qf[0][ch], c0, 0, 0, 0);
                    c1 = __builtin_amdgcn_mfma_f32_16x16x32_bf16(kf, qf[1][ch], c1, 0, 0, 0);
                }
                sT0[mb] = c0; sT1[mb] = c1;
            }
            __builtin_amdgcn_s_setprio(0);

            // ---- set 0: mask, exp, pack, permlane redistribute ----
            short8 pf0, pf1;
            {
                const int rs = q0 + wq * 32;
                const bool interior = (kv0 + 31 <= rs) && (rs + 15 - kv0 <= win);
                if (!interior) {
                    const int dbase = rs + l16 - kv0 - quad * 4;
#pragma unroll
                    for (int mb = 0; mb < 2; mb++)
#pragma unroll
                        for (int r = 0; r < 4; r++) {
                            const unsigned diff = (unsigned)(dbase - mb * 16 - r);
                            sT0[mb][r] = (diff <= (unsigned)win) ? sT0[mb][r] : -3.0e38f;
                        }
                }
                unsigned w[4];
#pragma unroll
                for (int mb = 0; mb < 2; mb++) {
                    float p0 = EXP2(sT0[mb][0]);
                    float p1 = EXP2(sT0[mb][1]);
                    float p2 = EXP2(sT0[mb][2]);
                    float p3 = EXP2(sT0[mb][3]);
                    lp0 += (p0 + p1) + (p2 + p3);
                    w[2 * mb]     = pk_bf16(p0, p1);
                    w[2 * mb + 1] = pk_bf16(p2, p3);
                }
                uint2v pa = __builtin_amdgcn_permlane32_swap(w[0], w[2], false, false);
                uint2v c02 = __builtin_amdgcn_permlane16_swap(pa[0], pa[1], false, false);
                uint2v pb = __builtin_amdgcn_permlane32_swap(w[1], w[3], false, false);
                uint2v c13 = __builtin_amdgcn_permlane16_swap(pb[0], pb[1], false, false);
                pf0 = mk8(c02[0], c13[0], c02[1], c13[1]);
            }
            // ---- set 1: fully independent of set 0 ----
            {
                const int rs = q0 + wq * 32 + 16;
                const bool interior = (kv0 + 31 <= rs) && (rs + 15 - kv0 <= win);
                if (!interior) {
                    const int dbase = rs + l16 - kv0 - quad * 4;
#pragma unroll
                    for (int mb = 0; mb < 2; mb++)
#pragma unroll
                        for (int r = 0; r < 4; r++) {
                            const unsigned diff = (unsigned)(dbase - mb * 16 - r);
                            sT1[mb][r] = (diff <= (unsigned)win) ? sT1[mb][r] : -3.0e38f;
                        }
                }
                unsigned w[4];
#pragma unroll
                for (int mb = 0; mb < 2; mb++) {
                    float p0 = EXP2(sT1[mb][0]);
                    float p1 = EXP2(sT1[mb][1]);
                    float p2 = EXP2(sT1[mb][2]);
                    float p3 = EXP2(sT1[mb][3]);
                    lp1 += (p0 + p1) + (p2 + p3);
                    w[2 * mb]     = pk_bf16(p0, p1);
                    w[2 * mb + 1] = pk_bf16(p2, p3);
                }
                uint2v pa = __builtin_amdgcn_permlane32_swap(w[0], w[2], false, false);
                uint2v c02 = __builtin_amdgcn_permlane16_swap(pa[0], pa[1], false, false);
                uint2v pb = __builtin_amdgcn_permlane32_swap(w[1], w[3], false, false);
                uint2v c13 = __builtin_amdgcn_permlane16_swap(pb[0], pb[1], false, false);
                pf1 = mk8(c02[0], c13[0], c02[1], c13[1]);
            }

            // ---- PV: vf read once serves both sets (K-dim 32 = 1 MFMA) ----
            __builtin_amdgcn_s_setprio(1);
#pragma unroll
            for (int nb = 0; nb < 4; nb++) {
                short8 vf = *(short8*)&Vg[(nb * 16 + l16) * 40 + quad * 8];
                acc[0][nb] = __builtin_amdgcn_mfma_f32_16x16x32_bf16(pf0, vf, acc[0][nb], 0, 0, 0);
                acc[1][nb] = __builtin_amdgcn_mfma_f32_16x16x32_bf16(pf1, vf, acc[1][nb], 0, 0, 0);
            }
            __builtin_amdgcn_s_setprio(0);
        }
        __syncthreads();   // B: compute done before next stage overwrites
    }

    // ---- l: cross-quad reduce (every lane -> full row sum for row l16) ----
    lp0 += __shfl_xor(lp0, 16); lp0 += __shfl_xor(lp0, 32);
    lp1 += __shfl_xor(lp1, 16); lp1 += __shfl_xor(lp1, 32);

    // ---- 4-way merge: A=g1, B=g3; g2 merges B, writes to A; g0 sums all ----
    float* fA = (float*)LDS;            // 64 rows x stride 66 = 16896 B
    float* fB = fA + 4224;              // second area, 16896 B (total 33792)
    if (g == 1 || g == 3) {
        float* fx = (g == 1) ? fA : fB;
#pragma unroll
        for (int s = 0; s < 2; s++) {
            if (quad == 0) fx[(wq * 32 + s * 16 + l16) * 66 + 64] = (s ? lp1 : lp0);
#pragma unroll
            for (int r = 0; r < 4; r++) {
                const int row = wq * 32 + s * 16 + quad * 4 + r;
#pragma unroll
                for (int nb = 0; nb < 4; nb++)
                    fx[row * 66 + nb * 16 + l16] = acc[s][nb][r];
            }
        }
    }
    __syncthreads();
    float lt0[2][4];
    if (g == 0) {
#pragma unroll
        for (int s = 0; s < 2; s++) {
            const float lps = s ? lp1 : lp0;
#pragma unroll
            for (int r = 0; r < 4; r++) {
                const int row = wq * 32 + s * 16 + quad * 4 + r;
                lt0[s][r] = __shfl(lps, quad * 4 + r) + fA[row * 66 + 64];
#pragma unroll
                for (int nb = 0; nb < 4; nb++)
                    acc[s][nb][r] += fA[row * 66 + nb * 16 + l16];
            }
        }
    }
    if (g == 2) {
#pragma unroll
        for (int s = 0; s < 2; s++)
#pragma unroll
            for (int r = 0; r < 4; r++) {
                const int row = wq * 32 + s * 16 + quad * 4 + r;
#pragma unroll
                for (int nb = 0; nb < 4; nb++)
                    acc[s][nb][r] += fB[row * 66 + nb * 16 + l16];
            }
    }
    __syncthreads();
    if (g == 2) {   // write merged (g2+g3) partial into area A
#pragma unroll
        for (int s = 0; s < 2; s++) {
            if (quad == 0) {
                const int row = wq * 32 + s * 16 + l16;
                fA[row * 66 + 64] = (s ? lp1 : lp0) + fB[row * 66 + 64];
            }
#pragma unroll
            for (int r = 0; r < 4; r++) {
                const int row = wq * 32 + s * 16 + quad * 4 + r;
#pragma unroll
                for (int nb = 0; nb < 4; nb++)
                    fA[row * 66 + nb * 16 + l16] = acc[s][nb][r];
            }
        }
    }
    __syncthreads();
    if (g == 0) {
#pragma unroll
        for (int s = 0; s < 2; s++) {
#pragma unroll
            for (int r = 0; r < 4; r++) {
                const int row = wq * 32 + s * 16 + quad * 4 + r;
                const float lt = lt0[s][r] + fA[row * 66 + 64];
                const float inv = 1.0f / lt;
                float* dst = Op + (size_t)(q0 + row) * Dc;
#pragma unroll
                for (int nb = 0; nb < 4; nb++)
                    dst[nb * 16 + l16] = (acc[s][nb][r] + fA[row * 66 + nb * 16 + l16]) * inv;
            }
        }
    }
}

extern "C" void kernel_launch(void* const* d_in, const int* in_sizes, int n_in,
                              void* d_out, int out_size, void* d_ws, size_t ws_size,
                              hipStream_t stream) {
    (void)in_sizes; (void)n_in; (void)ws_size; (void)out_size;
    const float* Q = (const float*)d_in[0];
    const float* K = (const float*)d_in[1];
    const float* V = (const float*)d_in[2];
    const int* wsz = (const int*)d_in[3];
    float* Out = (float*)d_out;

    unsigned short* Kb  = (unsigned short*)((char*)d_ws + KB_OFF);
    unsigned short* Vtb = (unsigned short*)((char*)d_ws + VB_OFF);

    // K bf16 convert (2048 blocks) + V^T bf16 (1024 blocks) — R12 proven.
    preconv_kernel<<<dim3(3072), dim3(256), 0, stream>>>(K, V, Kb, Vtb);
    // 1024 blocks x 512 thr: 4 blocks/CU x 8 waves = 32 waves/CU (8/SIMD).
    dswa_kernel<<<dim3(1024), dim3(512), 0, stream>>>(Q, Kb, Vtb, wsz, Out);
}

// Round 9
// 140.988 us; speedup vs baseline: 1.8358x; 1.8358x over previous
//
#include <hip/hip_runtime.h>
#include <hip/hip_bf16.h>

// DynamicSlidingWindowAttention — flash attention, bf16 MFMA, gfx950.
// R20: direct-from-L2 fragment reads using the PROVEN linear layouts.
//  * R19 post-mortem: 32 waves/CU demands <=64 unified regs/wave; working set
//    ~120 => catastrophic spill (VGPR 32, WRITE_SIZE 414MB). Occupancy lever
//    is register-capped at 16 waves/CU — closed permanently.
//  * R16/R17 failed on a NEW repacked layout; R18 failed on doubled staging.
//    This round: NO new layouts, NO staging. Read fragments directly from
//    R12's proven Kb (row-major bf16) and Vtb (V^T row-major bf16) with the
//    exact index expressions the LDS path used:
//      kf(mb,ch) = Kb[(kv0+mb*16+l16)*64 + ch*32 + quad*8]   (16B/lane)
//      vf(nb)    = Vtb[(nb*16+l16)*2048 + kv0 + quad*8]      (16B/lane)
//    K/V are L2-resident (256KB/head, 32 sharing blocks). Main loop has
//    ZERO LDS ops and ZERO barriers; waves fully independent.
//  * Latency hiding in-iteration: vf issued after QK, consumed after softmax
//    (~300cy gap); next tile's kf issued before softmax, consumed next iter.
//  * LDS = epilogue merge buffer only (16896 B).
// R12 retained verbatim: preconv (K bf16 + V^T bf16), balanced static decode,
// Q frag load, S^T MFMA order, mask/exp, permlane32+16 P redistribution,
// 2-group epilogue merge. setprio retained.
// Layouts (m89/m91/m120-verified):
//   mfma_f32_16x16x32_bf16: A[m=lane&15][k=quad*8+j], B[k=quad*8+j][n=lane&15],
//   C/D: col=lane&15, row=quad*4+reg.

constexpr int Bc = 2, Hc = 16, Tc = 2048, Dc = 64;
constexpr int BQ = 64;            // q rows per block/item
constexpr int BK = 32;            // keys per kv tile
constexpr float QSCALE = 0.125f * 1.44269504088896340736f;  // 1/sqrt(d)*log2e
constexpr float CMAX = 16.0f;     // static softmax max (log2 domain)

// d_ws layout (bytes): [256,+8MiB) K bf16 | then V^T bf16
constexpr size_t KB_OFF = 256;
constexpr size_t VB_OFF = 256 + (size_t)Bc * Hc * Tc * Dc * 2;
constexpr int HEADE = Tc * Dc;

typedef __attribute__((ext_vector_type(8))) short short8;
typedef __attribute__((ext_vector_type(4))) float float4v;
typedef __attribute__((ext_vector_type(2))) unsigned int uint2v;

#if defined(__has_builtin)
#if __has_builtin(__builtin_amdgcn_exp2f)
#define EXP2 __builtin_amdgcn_exp2f
#endif
#endif
#ifndef EXP2
#define EXP2 exp2f
#endif

__device__ inline unsigned f2bf_u(float f) {
    union { float f; unsigned u; } v; v.f = f;
    return (v.u + 0x7fffu + ((v.u >> 16) & 1u)) >> 16;   // RNE
}

__device__ inline short8 pack8(const float* t) {
    short8 r;
#pragma unroll
    for (int j = 0; j < 8; j++) r[j] = (short)f2bf_u(t[j]);
    return r;
}

__device__ inline unsigned pk_bf16(float a, float b) {
    __hip_bfloat162 h = __float22bfloat162_rn(make_float2(a, b));
    union { __hip_bfloat162 h; unsigned u; } v; v.h = h;
    return v.u;
}

__device__ inline short8 mk8(unsigned a0, unsigned a1, unsigned a2, unsigned a3) {
    union { unsigned u[4]; short8 s; } v;
    v.u[0] = a0; v.u[1] = a1; v.u[2] = a2; v.u[3] = a3;
    return v.s;
}

// ---- pre-pass: K convert + V transpose-convert (R12 proven, verbatim) ----
__global__ __launch_bounds__(256)
void preconv_kernel(const float* __restrict__ K, const float* __restrict__ V,
                    unsigned short* __restrict__ Kb, unsigned short* __restrict__ Vtb) {
    const int blk = blockIdx.x;
    const int tid = threadIdx.x;
    if (blk < 2048) {
        const int base = blk * 2048 + tid * 8;
        float4v a = *(const float4v*)(K + base);
        float4v b = *(const float4v*)(K + base + 4);
        float t[8] = {a[0], a[1], a[2], a[3], b[0], b[1], b[2], b[3]};
        *(short8*)(Kb + base) = pack8(t);
    } else {
        __shared__ float tile[64][65];
        const int blk2 = blk - 2048;
        const int bh = blk2 >> 5;
        const int t0 = (blk2 & 31) * 64;
        const float* src = V + (size_t)bh * HEADE + (size_t)t0 * Dc;
#pragma unroll
        for (int i = 0; i < 4; i++) {
            const int r = (tid >> 4) + i * 16;
            const int d4 = (tid & 15) * 4;
            float4v v4 = *(const float4v*)(src + r * Dc + d4);
            tile[r][d4] = v4[0]; tile[r][d4 + 1] = v4[1];
            tile[r][d4 + 2] = v4[2]; tile[r][d4 + 3] = v4[3];
        }
        __syncthreads();
        unsigned short* dst = Vtb + (size_t)bh * HEADE + t0;
#pragma unroll
        for (int i = 0; i < 2; i++) {
            const int d = (tid >> 3) + 32 * i;
            const int c = tid & 7;
            float t[8];
#pragma unroll
            for (int j = 0; j < 8; j++) t[j] = tile[c * 8 + j][d];
            *(short8*)(dst + (size_t)d * Tc + c * 8) = pack8(t);
        }
    }
}

__global__ __launch_bounds__(256, 4)
void dswa_kernel(const float* __restrict__ Q,
                 const unsigned short* __restrict__ Kb,
                 const unsigned short* __restrict__ Vtb,
                 const int* __restrict__ wsz,
                 float* __restrict__ O) {
    __shared__ __align__(16) float fl[4224];   // epilogue only: 64 x 66 floats

    const int tid  = threadIdx.x;
    const int wave = tid >> 6;          // 0..3
    const int g    = wave >> 1;         // kv-split group 0/1
    const int wq   = wave & 1;          // 32-row q half
    const int lane = tid & 63;
    const int quad = lane >> 4;
    const int l16  = lane & 15;

    // ---- balanced static item decode (bijection on (b,h,qt), proven) ----
    const int blk  = blockIdx.x;
    const int ci   = blk & 255;
    const int slot = blk >> 8;               // 0=FULL,1=w1024,2=w512,3=w256
    const int b    = ci & 1;
    const int q5   = (ci >> 1) & 31;
    const int hh   = ci >> 6;
    const int h    = (3 - slot) * 4 + hh;
    const int qt   = (slot == 0) ? q5 : 31 - q5;
    const int q0   = qt * BQ;
    const int win  = wsz[h];

    const size_t headoff = (size_t)(b * Hc + h) * HEADE;
    const float* Qp = Q + headoff;
    const unsigned short* Kbh = Kb + headoff;
    const unsigned short* Vbh = Vtb + headoff;
    float* Op = O + headoff;

    // ---- Q fragments for both 16-row sets, pre-scaled (log2 domain) ----
    short8 qf[2][2];
#pragma unroll
    for (int s = 0; s < 2; s++) {
        const int qrow = q0 + wq * 32 + s * 16 + l16;
#pragma unroll
        for (int c = 0; c < 2; c++) {
            const float* src = Qp + (size_t)qrow * Dc + c * 32 + quad * 8;
            float4v a = *(const float4v*)src;
            float4v d4 = *(const float4v*)(src + 4);
            float t[8] = {a[0]*QSCALE, a[1]*QSCALE, a[2]*QSCALE, a[3]*QSCALE,
                          d4[0]*QSCALE, d4[1]*QSCALE, d4[2]*QSCALE, d4[3]*QSCALE};
            qf[s][c] = pack8(t);
        }
    }

    float4v acc[2][4];   // [set][nb] unnormalized O
#pragma unroll
    for (int s = 0; s < 2; s++)
#pragma unroll
        for (int nb = 0; nb < 4; nb++) acc[s][nb] = (float4v){0.f, 0.f, 0.f, 0.f};
    float lp0 = 0.0f, lp1 = 0.0f;

    const int kv_lo = (max(0, q0 - win)) & ~(BK - 1);
    const int C = (q0 + BQ - kv_lo) >> 5;    // 32-key tiles (>= 2)

    // per-lane fragment base offsets (shorts)
    //   kf: (kv0 + mb*16 + l16)*64 + ch*32 + quad*8
    //   vf: (nb*16 + l16)*Tc + kv0 + quad*8
    const unsigned short* kbase = Kbh + (size_t)l16 * Dc + quad * 8;
    const unsigned short* vbase = Vbh + (size_t)l16 * Tc + quad * 8;

    // ---- prologue: kf for tile g (direct L2) ----
    short8 k0, k1, k2, k3;
    {
        const unsigned short* kp = kbase + (size_t)(kv_lo + g * BK) * Dc;
        k0 = *(const short8*)(kp);                 // mb0 ch0
        k1 = *(const short8*)(kp + 16 * Dc);       // mb1 ch0
        k2 = *(const short8*)(kp + 32);            // mb0 ch1
        k3 = *(const short8*)(kp + 16 * Dc + 32);  // mb1 ch1
    }

    // ---- barrier-free, LDS-free main loop ----
    for (int ti = g; ti < C; ti += 2) {
        const int kv0 = kv_lo + ti * BK;

        // ---- S^T = K Q^T - CMAX, both sets share kf ----
        float4v sT0[2], sT1[2];
        __builtin_amdgcn_s_setprio(1);
        {
            float4v c0 = {-CMAX, -CMAX, -CMAX, -CMAX};
            float4v c1 = c0, c2 = c0, c3 = c0;
            c0 = __builtin_amdgcn_mfma_f32_16x16x32_bf16(k0, qf[0][0], c0, 0, 0, 0);
            c1 = __builtin_amdgcn_mfma_f32_16x16x32_bf16(k0, qf[1][0], c1, 0, 0, 0);
            c2 = __builtin_amdgcn_mfma_f32_16x16x32_bf16(k1, qf[0][0], c2, 0, 0, 0);
            c3 = __builtin_amdgcn_mfma_f32_16x16x32_bf16(k1, qf[1][0], c3, 0, 0, 0);
            c0 = __builtin_amdgcn_mfma_f32_16x16x32_bf16(k2, qf[0][1], c0, 0, 0, 0);
            c1 = __builtin_amdgcn_mfma_f32_16x16x32_bf16(k2, qf[1][1], c1, 0, 0, 0);
            c2 = __builtin_amdgcn_mfma_f32_16x16x32_bf16(k3, qf[0][1], c2, 0, 0, 0);
            c3 = __builtin_amdgcn_mfma_f32_16x16x32_bf16(k3, qf[1][1], c3, 0, 0, 0);
            sT0[0] = c0; sT1[0] = c1; sT0[1] = c2; sT1[1] = c3;
        }
        __builtin_amdgcn_s_setprio(0);

        // ---- issue V fragment loads (consumed after softmax, ~300cy gap) ----
        const unsigned short* vp = vbase + kv0;
        short8 vf0 = *(const short8*)(vp);
        short8 vf1 = *(const short8*)(vp + 16 * Tc);
        short8 vf2 = *(const short8*)(vp + 32 * Tc);
        short8 vf3 = *(const short8*)(vp + 48 * Tc);

        // ---- issue next tile's K loads (consumed next iteration) ----
        if (ti + 2 < C) {
            const unsigned short* kp = kbase + (size_t)(kv0 + 2 * BK) * Dc;
            k0 = *(const short8*)(kp);
            k1 = *(const short8*)(kp + 16 * Dc);
            k2 = *(const short8*)(kp + 32);
            k3 = *(const short8*)(kp + 16 * Dc + 32);
        }

        // ---- set 0: mask, exp, pack, permlane redistribute ----
        short8 pf0, pf1;
        {
            const int rs = q0 + wq * 32;
            const bool interior = (kv0 + 31 <= rs) && (rs + 15 - kv0 <= win);
            if (!interior) {
                const int dbase = rs + l16 - kv0 - quad * 4;
#pragma unroll
                for (int mb = 0; mb < 2; mb++)
#pragma unroll
                    for (int r = 0; r < 4; r++) {
                        const unsigned diff = (unsigned)(dbase - mb * 16 - r);
                        sT0[mb][r] = (diff <= (unsigned)win) ? sT0[mb][r] : -3.0e38f;
                    }
            }
            unsigned w[4];
#pragma unroll
            for (int mb = 0; mb < 2; mb++) {
                float p0 = EXP2(sT0[mb][0]);
                float p1 = EXP2(sT0[mb][1]);
                float p2 = EXP2(sT0[mb][2]);
                float p3 = EXP2(sT0[mb][3]);
                lp0 += (p0 + p1) + (p2 + p3);
                w[2 * mb]     = pk_bf16(p0, p1);
                w[2 * mb + 1] = pk_bf16(p2, p3);
            }
            uint2v pa = __builtin_amdgcn_permlane32_swap(w[0], w[2], false, false);
            uint2v c02 = __builtin_amdgcn_permlane16_swap(pa[0], pa[1], false, false);
            uint2v pb = __builtin_amdgcn_permlane32_swap(w[1], w[3], false, false);
            uint2v c13 = __builtin_amdgcn_permlane16_swap(pb[0], pb[1], false, false);
            pf0 = mk8(c02[0], c13[0], c02[1], c13[1]);
        }
        // ---- set 1: fully independent of set 0 ----
        {
            const int rs = q0 + wq * 32 + 16;
            const bool interior = (kv0 + 31 <= rs) && (rs + 15 - kv0 <= win);
            if (!interior) {
                const int dbase = rs + l16 - kv0 - quad * 4;
#pragma unroll
                for (int mb = 0; mb < 2; mb++)
#pragma unroll
                    for (int r = 0; r < 4; r++) {
                        const unsigned diff = (unsigned)(dbase - mb * 16 - r);
                        sT1[mb][r] = (diff <= (unsigned)win) ? sT1[mb][r] : -3.0e38f;
                    }
            }
            unsigned w[4];
#pragma unroll
            for (int mb = 0; mb < 2; mb++) {
                float p0 = EXP2(sT1[mb][0]);
                float p1 = EXP2(sT1[mb][1]);
                float p2 = EXP2(sT1[mb][2]);
                float p3 = EXP2(sT1[mb][3]);
                lp1 += (p0 + p1) + (p2 + p3);
                w[2 * mb]     = pk_bf16(p0, p1);
                w[2 * mb + 1] = pk_bf16(p2, p3);
            }
            uint2v pa = __builtin_amdgcn_permlane32_swap(w[0], w[2], false, false);
            uint2v c02 = __builtin_amdgcn_permlane16_swap(pa[0], pa[1], false, false);
            uint2v pb = __builtin_amdgcn_permlane32_swap(w[1], w[3], false, false);
            uint2v c13 = __builtin_amdgcn_permlane16_swap(pb[0], pb[1], false, false);
            pf1 = mk8(c02[0], c13[0], c02[1], c13[1]);
        }

        // ---- PV: direct vf fragments serve both sets ----
        __builtin_amdgcn_s_setprio(1);
        acc[0][0] = __builtin_amdgcn_mfma_f32_16x16x32_bf16(pf0, vf0, acc[0][0], 0, 0, 0);
        acc[1][0] = __builtin_amdgcn_mfma_f32_16x16x32_bf16(pf1, vf0, acc[1][0], 0, 0, 0);
        acc[0][1] = __builtin_amdgcn_mfma_f32_16x16x32_bf16(pf0, vf1, acc[0][1], 0, 0, 0);
        acc[1][1] = __builtin_amdgcn_mfma_f32_16x16x32_bf16(pf1, vf1, acc[1][1], 0, 0, 0);
        acc[0][2] = __builtin_amdgcn_mfma_f32_16x16x32_bf16(pf0, vf2, acc[0][2], 0, 0, 0);
        acc[1][2] = __builtin_amdgcn_mfma_f32_16x16x32_bf16(pf1, vf2, acc[1][2], 0, 0, 0);
        acc[0][3] = __builtin_amdgcn_mfma_f32_16x16x32_bf16(pf0, vf3, acc[0][3], 0, 0, 0);
        acc[1][3] = __builtin_amdgcn_mfma_f32_16x16x32_bf16(pf1, vf3, acc[1][3], 0, 0, 0);
        __builtin_amdgcn_s_setprio(0);
    }

    // ---- l: cross-quad reduce ----
    lp0 += __shfl_xor(lp0, 16); lp0 += __shfl_xor(lp0, 32);
    lp1 += __shfl_xor(lp1, 16); lp1 += __shfl_xor(lp1, 32);

    // ---- merge the two KV-split partials (pure adds), store ----
    __syncthreads();
    if (g == 1) {
#pragma unroll
        for (int s = 0; s < 2; s++) {
            if (quad == 0) fl[(wq * 32 + s * 16 + l16) * 66 + 64] = (s ? lp1 : lp0);
#pragma unroll
            for (int r = 0; r < 4; r++) {
                const int row = wq * 32 + s * 16 + quad * 4 + r;
#pragma unroll
                for (int nb = 0; nb < 4; nb++)
                    fl[row * 66 + nb * 16 + l16] = acc[s][nb][r];
            }
        }
    }
    __syncthreads();
    if (g == 0) {
#pragma unroll
        for (int s = 0; s < 2; s++) {
            const float lps = s ? lp1 : lp0;
#pragma unroll
            for (int r = 0; r < 4; r++) {
                const int row = wq * 32 + s * 16 + quad * 4 + r;
                const float l0 = __shfl(lps, quad * 4 + r);
                const float lt = l0 + fl[row * 66 + 64];
                const float inv = 1.0f / lt;
                float* dst = Op + (size_t)(q0 + row) * Dc;
#pragma unroll
                for (int nb = 0; nb < 4; nb++)
                    dst[nb * 16 + l16] = (acc[s][nb][r] + fl[row * 66 + nb * 16 + l16]) * inv;
            }
        }
    }
}

extern "C" void kernel_launch(void* const* d_in, const int* in_sizes, int n_in,
                              void* d_out, int out_size, void* d_ws, size_t ws_size,
                              hipStream_t stream) {
    (void)in_sizes; (void)n_in; (void)ws_size; (void)out_size;
    const float* Q = (const float*)d_in[0];
    const float* K = (const float*)d_in[1];
    const float* V = (const float*)d_in[2];
    const int* wsz = (const int*)d_in[3];
    float* Out = (float*)d_out;

    unsigned short* Kb  = (unsigned short*)((char*)d_ws + KB_OFF);
    unsigned short* Vtb = (unsigned short*)((char*)d_ws + VB_OFF);

    // K bf16 convert (2048 blocks) + V^T bf16 (1024 blocks) — R12 proven.
    preconv_kernel<<<dim3(3072), dim3(256), 0, stream>>>(K, V, Kb, Vtb);
    // 1024 blocks = 4/CU; barrier-free, LDS-free main loop; direct-L2 frags.
    dswa_kernel<<<dim3(1024), dim3(256), 0, stream>>>(Q, Kb, Vtb, wsz, Out);
}